// Round 1
// baseline (1137.495 us; speedup 1.0000x reference)
//
#include <hip/hip_runtime.h>

// 2-layer GCN: out = gcn(relu(gcn(x,W1,b1,e0)), W2, b2, e1)
// gcn(x,W,b,e): deg = indeg(dst)+1 (self-loop); dinv = rsqrt(deg)
//               h = x@W;  out[v] = sum_{e:dst=v} h[src]*dinv[src]*dinv[v]
//                          + h[v]*dinv[v]^2 + b
// Strategy: device-built CSR (histogram -> scan -> fill), then pull-mode
// aggregation: one wave per node, lane = feature, no float atomics.

__global__ __launch_bounds__(256) void k_hist(const int* __restrict__ dst,
                                              int* __restrict__ cnt, int E) {
  int stride = gridDim.x * blockDim.x;
  for (int i = blockIdx.x * blockDim.x + threadIdx.x; i < E; i += stride)
    atomicAdd(&cnt[dst[i]], 1);
}

__global__ __launch_bounds__(256) void k_dinv(const int* __restrict__ cnt,
                                              float* __restrict__ dinv, int N) {
  int i = blockIdx.x * blockDim.x + threadIdx.x;
  if (i < N) dinv[i] = rsqrtf((float)(cnt[i] + 1));  // deg >= 1 always
}

// Block-level scan: 256 threads x 4 items = 1024 elements/block.
// Writes per-element block-local exclusive prefix to off[], block total to bsum[].
__global__ __launch_bounds__(256) void k_scan1(const int* __restrict__ cnt,
                                               int* __restrict__ off,
                                               int* __restrict__ bsum, int N) {
  __shared__ int wsum[4];
  int t = threadIdx.x;
  int base = blockIdx.x * 1024 + t * 4;
  int v0 = (base + 0 < N) ? cnt[base + 0] : 0;
  int v1 = (base + 1 < N) ? cnt[base + 1] : 0;
  int v2 = (base + 2 < N) ? cnt[base + 2] : 0;
  int v3 = (base + 3 < N) ? cnt[base + 3] : 0;
  int tsum = v0 + v1 + v2 + v3;
  int lane = t & 63;
  int x = tsum;
#pragma unroll
  for (int d = 1; d < 64; d <<= 1) {   // inclusive wave scan (wave = 64)
    int y = __shfl_up(x, d, 64);
    if (lane >= d) x += y;
  }
  int wid = t >> 6;
  if (lane == 63) wsum[wid] = x;
  __syncthreads();
  int wofs = 0;
  for (int ww = 0; ww < wid; ++ww) wofs += wsum[ww];  // LDS broadcast, tiny
  int excl = wofs + x - tsum;  // block-local exclusive prefix
  if (base + 0 < N) off[base + 0] = excl;
  if (base + 1 < N) off[base + 1] = excl + v0;
  if (base + 2 < N) off[base + 2] = excl + v0 + v1;
  if (base + 3 < N) off[base + 3] = excl + v0 + v1 + v2;
  if (t == 255) bsum[blockIdx.x] = wofs + x;  // block total
}

// Single-block exclusive scan of block totals (nb <= 128; here nb = 98).
__global__ __launch_bounds__(128) void k_scan2(int* __restrict__ bsum, int nb) {
  __shared__ int tmp[128];
  int t = threadIdx.x;
  int v = (t < nb) ? bsum[t] : 0;
  tmp[t] = v;
  __syncthreads();
#pragma unroll
  for (int d = 1; d < 128; d <<= 1) {
    int y = (t >= d) ? tmp[t - d] : 0;
    __syncthreads();
    tmp[t] += y;
    __syncthreads();
  }
  if (t < nb) bsum[t] = tmp[t] - v;  // exclusive
}

__global__ __launch_bounds__(256) void k_scan3(int* __restrict__ off,
                                               int* __restrict__ cur,
                                               const int* __restrict__ bsum, int N) {
  int i = blockIdx.x * blockDim.x + threadIdx.x;
  if (i < N) {
    int o = off[i] + bsum[i >> 10];
    off[i] = o;
    cur[i] = o;  // fill-cursor copy
  }
}

__global__ __launch_bounds__(256) void k_fill(const int* __restrict__ src,
                                              const int* __restrict__ dst,
                                              int* __restrict__ cur,
                                              int* __restrict__ csr, int E) {
  int stride = gridDim.x * blockDim.x;
  for (int i = blockIdx.x * blockDim.x + threadIdx.x; i < E; i += stride) {
    int p = atomicAdd(&cur[dst[i]], 1);
    csr[p] = src[i];
  }
}

// H[v][j] = sum_k X[v][k] * W[k][j].  W (16 KB) staged in LDS once per block;
// 4 nodes per block-iteration staged in LDS (coalesced), grid-stride.
__global__ __launch_bounds__(256) void k_gemm64(const float* __restrict__ X,
                                                const float* __restrict__ W,
                                                float* __restrict__ H, int N) {
  __shared__ float Wl[4096];
  __shared__ float Xl[256];
  for (int t = threadIdx.x; t < 4096; t += 256) Wl[t] = W[t];
  int j = threadIdx.x & 63;   // output feature (lane)
  int nl = threadIdx.x >> 6;  // node-in-block 0..3
  for (int base = blockIdx.x * 4; base < N; base += gridDim.x * 4) {
    __syncthreads();
    int gi = base * 64 + threadIdx.x;
    Xl[threadIdx.x] = (gi < N * 64) ? X[gi] : 0.f;
    __syncthreads();
    int v = base + nl;
    if (v < N) {
      float acc = 0.f;
#pragma unroll
      for (int k = 0; k < 64; k += 4) {  // Wl stride-1 across lanes: 2-way, free
        acc = fmaf(Xl[nl * 64 + k + 0], Wl[(k + 0) * 64 + j], acc);
        acc = fmaf(Xl[nl * 64 + k + 1], Wl[(k + 1) * 64 + j], acc);
        acc = fmaf(Xl[nl * 64 + k + 2], Wl[(k + 2) * 64 + j], acc);
        acc = fmaf(Xl[nl * 64 + k + 3], Wl[(k + 3) * 64 + j], acc);
      }
      H[v * 64 + j] = acc;
    }
  }
}

// Pull-mode aggregation: one wave per node, lane = feature.
// 4-edge unroll keeps 4 independent 256B row-gathers in flight.
template <bool RELU>
__global__ __launch_bounds__(256) void k_agg(const float* __restrict__ H,
                                             const int* __restrict__ csr,
                                             const int* __restrict__ off,
                                             const int* __restrict__ cnt,
                                             const float* __restrict__ dinv,
                                             const float* __restrict__ bias,
                                             float* __restrict__ out, int N) {
  int wid = (blockIdx.x * blockDim.x + threadIdx.x) >> 6;  // node
  int lane = threadIdx.x & 63;                             // feature
  if (wid >= N) return;
  float dv = dinv[wid];
  float acc = H[wid * 64 + lane] * (dv * dv);  // self-loop
  int beg = off[wid];
  int num = cnt[wid];
  int i = 0;
  for (; i + 4 <= num; i += 4) {
    int s0 = csr[beg + i + 0], s1 = csr[beg + i + 1];
    int s2 = csr[beg + i + 2], s3 = csr[beg + i + 3];
    float w0 = dinv[s0], w1 = dinv[s1], w2 = dinv[s2], w3 = dinv[s3];
    float h0 = H[s0 * 64 + lane], h1 = H[s1 * 64 + lane];
    float h2 = H[s2 * 64 + lane], h3 = H[s3 * 64 + lane];
    acc = fmaf(h0, w0 * dv, acc);
    acc = fmaf(h1, w1 * dv, acc);
    acc = fmaf(h2, w2 * dv, acc);
    acc = fmaf(h3, w3 * dv, acc);
  }
  for (; i < num; ++i) {
    int s = csr[beg + i];
    acc = fmaf(H[s * 64 + lane], dinv[s] * dv, acc);
  }
  acc += bias[lane];
  if (RELU) acc = fmaxf(acc, 0.f);
  out[wid * 64 + lane] = acc;
}

extern "C" void kernel_launch(void* const* d_in, const int* in_sizes, int n_in,
                              void* d_out, int out_size, void* d_ws, size_t ws_size,
                              hipStream_t stream) {
  const float* x  = (const float*)d_in[0];
  const float* W1 = (const float*)d_in[1];
  const float* b1 = (const float*)d_in[2];
  const float* W2 = (const float*)d_in[3];
  const float* b2 = (const float*)d_in[4];
  const int*   e0 = (const int*)d_in[5];
  const int*   e1 = (const int*)d_in[6];
  float* out = (float*)d_out;

  const int N = in_sizes[0] / 64;   // 100000
  const int E = in_sizes[5] / 2;    // 3200000
  const int* src0 = e0;     const int* dst0 = e0 + E;
  const int* src1 = e1;     const int* dst1 = e1 + E;

  // workspace carve (~55 MB total)
  char* w = (char*)d_ws;
  size_t o = 0;
  auto carve = [&](size_t bytes) -> void* {
    void* p = w + o;
    o = (o + bytes + 255) & ~(size_t)255;
    return p;
  };
  int* cnt12 = (int*)carve((size_t)2 * N * 4);
  int* cnt1 = cnt12;
  int* cnt2 = cnt12 + N;
  int* off1 = (int*)carve((size_t)N * 4);
  int* off2 = (int*)carve((size_t)N * 4);
  int* cur1 = (int*)carve((size_t)N * 4);
  int* cur2 = (int*)carve((size_t)N * 4);
  float* dinv1 = (float*)carve((size_t)N * 4);
  float* dinv2 = (float*)carve((size_t)N * 4);
  int* bsum = (int*)carve(512 * 4);
  int* csr1 = (int*)carve((size_t)E * 4);
  int* csr2 = (int*)carve((size_t)E * 4);
  float* H = (float*)carve((size_t)N * 64 * 4);

  const int NB = (N + 1023) / 1024;       // 98 (<= 128 required by k_scan2)
  const int nblk = (N + 255) / 256;
  const int aggblk = (N * 64 + 255) / 256;  // 25000

  hipMemsetAsync(cnt12, 0, (size_t)2 * N * 4, stream);

  // CSR build, both layers
  k_hist<<<2048, 256, 0, stream>>>(dst0, cnt1, E);
  k_hist<<<2048, 256, 0, stream>>>(dst1, cnt2, E);
  k_dinv<<<nblk, 256, 0, stream>>>(cnt1, dinv1, N);
  k_dinv<<<nblk, 256, 0, stream>>>(cnt2, dinv2, N);
  k_scan1<<<NB, 256, 0, stream>>>(cnt1, off1, bsum, N);
  k_scan2<<<1, 128, 0, stream>>>(bsum, NB);
  k_scan3<<<nblk, 256, 0, stream>>>(off1, cur1, bsum, N);
  k_scan1<<<NB, 256, 0, stream>>>(cnt2, off2, bsum, N);
  k_scan2<<<1, 128, 0, stream>>>(bsum, NB);
  k_scan3<<<nblk, 256, 0, stream>>>(off2, cur2, bsum, N);
  k_fill<<<2048, 256, 0, stream>>>(src0, dst0, cur1, csr1, E);
  k_fill<<<2048, 256, 0, stream>>>(src1, dst1, cur2, csr2, E);

  // layer 1: h = x@W1 -> H; d_out = relu(agg1(H) + b1)  (d_out as scratch)
  k_gemm64<<<2048, 256, 0, stream>>>(x, W1, H, N);
  k_agg<true><<<aggblk, 256, 0, stream>>>(H, csr1, off1, cnt1, dinv1, b1, out, N);

  // layer 2: H = d_out@W2; d_out = agg2(H) + b2
  k_gemm64<<<2048, 256, 0, stream>>>(out, W2, H, N);
  k_agg<false><<<aggblk, 256, 0, stream>>>(H, csr2, off2, cnt2, dinv2, b2, out, N);
}

// Round 2
// 909.218 us; speedup vs baseline: 1.2511x; 1.2511x over previous
//
#include <hip/hip_runtime.h>

// 2-layer GCN: out = gcn(relu(gcn(x,W1,b1,e0)), W2, b2, e1)
// CSR built per call via two-level partition to kill scatter write-amp:
//   R1 finding: single-pass atomic-cursor fill wrote 196MB HBM for a 12.8MB
//   CSR (random 4B stores -> partial-line evictions, cross-XCD line bounce).
//   Fix: bucket by dst>>8 (391 buckets), block-local LDS histogram + chunk
//   reservation -> dense packed writes; then per-bucket fine fill where each
//   bucket's 32KB csr window is owned by ONE workgroup.

#define NPB   256   // nodes per bucket
#define BSH   8     // shift
#define BMSK  255
#define EPT   64    // edges per thread in k_bscatter
#define CHUNK (EPT * 256)

__global__ __launch_bounds__(256) void k_hist(const int* __restrict__ dst,
                                              int* __restrict__ cnt, int E) {
  int stride = gridDim.x * blockDim.x;
  for (int i = blockIdx.x * blockDim.x + threadIdx.x; i < E; i += stride)
    atomicAdd(&cnt[dst[i]], 1);
}

__global__ __launch_bounds__(256) void k_dinv(const int* __restrict__ cnt,
                                              float* __restrict__ dinv, int N) {
  int i = blockIdx.x * blockDim.x + threadIdx.x;
  if (i < N) dinv[i] = rsqrtf((float)(cnt[i] + 1));  // deg >= 1 (self-loop)
}

// Block-level scan: 256 threads x 4 items = 1024 elements/block.
__global__ __launch_bounds__(256) void k_scan1(const int* __restrict__ cnt,
                                               int* __restrict__ off,
                                               int* __restrict__ bsum, int N) {
  __shared__ int wsum[4];
  int t = threadIdx.x;
  int base = blockIdx.x * 1024 + t * 4;
  int v0 = (base + 0 < N) ? cnt[base + 0] : 0;
  int v1 = (base + 1 < N) ? cnt[base + 1] : 0;
  int v2 = (base + 2 < N) ? cnt[base + 2] : 0;
  int v3 = (base + 3 < N) ? cnt[base + 3] : 0;
  int tsum = v0 + v1 + v2 + v3;
  int lane = t & 63;
  int x = tsum;
#pragma unroll
  for (int d = 1; d < 64; d <<= 1) {
    int y = __shfl_up(x, d, 64);
    if (lane >= d) x += y;
  }
  int wid = t >> 6;
  if (lane == 63) wsum[wid] = x;
  __syncthreads();
  int wofs = 0;
  for (int ww = 0; ww < wid; ++ww) wofs += wsum[ww];
  int excl = wofs + x - tsum;
  if (base + 0 < N) off[base + 0] = excl;
  if (base + 1 < N) off[base + 1] = excl + v0;
  if (base + 2 < N) off[base + 2] = excl + v0 + v1;
  if (base + 3 < N) off[base + 3] = excl + v0 + v1 + v2;
  if (t == 255) bsum[blockIdx.x] = wofs + x;
}

__global__ __launch_bounds__(128) void k_scan2(int* __restrict__ bsum, int nb) {
  __shared__ int tmp[128];
  int t = threadIdx.x;
  int v = (t < nb) ? bsum[t] : 0;
  tmp[t] = v;
  __syncthreads();
#pragma unroll
  for (int d = 1; d < 128; d <<= 1) {
    int y = (t >= d) ? tmp[t - d] : 0;
    __syncthreads();
    tmp[t] += y;
    __syncthreads();
  }
  if (t < nb) bsum[t] = tmp[t] - v;  // exclusive
}

__global__ __launch_bounds__(256) void k_scan3(int* __restrict__ off,
                                               const int* __restrict__ bsum, int N) {
  int i = blockIdx.x * blockDim.x + threadIdx.x;
  if (i < N) off[i] += bsum[i >> 10];
}

// Partition edges into dst-buckets. Packed entry: (src<<8) | (dst&255).
// gcur0[b] zero-initialized; bucket base in packed[] is off[b<<8] (node scan).
__global__ __launch_bounds__(256) void k_bscatter(const int* __restrict__ src,
                                                  const int* __restrict__ dst,
                                                  const int* __restrict__ off,
                                                  int* __restrict__ gcur0,
                                                  int* __restrict__ packed,
                                                  int E, int B) {
  __shared__ int bh[512];
  __shared__ int bbase[512];
  int t = threadIdx.x;
  for (int b = t; b < B; b += 256) bh[b] = 0;
  __syncthreads();
  int e0 = blockIdx.x * CHUNK;
#pragma unroll 4
  for (int k = 0; k < EPT; ++k) {
    int i = e0 + k * 256 + t;
    if (i < E) atomicAdd(&bh[dst[i] >> BSH], 1);
  }
  __syncthreads();
  for (int b = t; b < B; b += 256) {
    int c = bh[b];
    if (c) bbase[b] = off[b << BSH] + atomicAdd(&gcur0[b], c);
    bh[b] = 0;  // reuse as local cursor
  }
  __syncthreads();
#pragma unroll 4
  for (int k = 0; k < EPT; ++k) {
    int i = e0 + k * 256 + t;
    if (i < E) {
      int d = dst[i];
      int b = d >> BSH;
      int loc = atomicAdd(&bh[b], 1);
      packed[bbase[b] + loc] = (src[i] << BSH) | (d & BMSK);
    }
  }
}

// Fine fill: one workgroup per bucket; LDS per-node cursors; csr writes land
// in this bucket's contiguous window (single-CU ownership -> dense lines).
__global__ __launch_bounds__(256) void k_fill2(const int* __restrict__ packed,
                                               const int* __restrict__ off,
                                               int* __restrict__ csr,
                                               int N, int E, int B) {
  __shared__ int curL[NPB];
  int t = threadIdx.x;
  int b = blockIdx.x;
  int node0 = b << BSH;
  int v = node0 + t;
  curL[t] = (v < N) ? off[v] : 0;
  int beg = off[node0];
  int end = (b == B - 1) ? E : off[node0 + NPB];
  __syncthreads();
  for (int i = beg + t; i < end; i += 256) {
    int e = packed[i];
    int p = atomicAdd(&curL[e & BMSK], 1);
    csr[p] = e >> BSH;
  }
}

// H = X @ W (64x64 W in LDS; 4 nodes per block-iter, grid-stride).
__global__ __launch_bounds__(256) void k_gemm64(const float* __restrict__ X,
                                                const float* __restrict__ W,
                                                float* __restrict__ H, int N) {
  __shared__ float Wl[4096];
  __shared__ float Xl[256];
  for (int t = threadIdx.x; t < 4096; t += 256) Wl[t] = W[t];
  int j = threadIdx.x & 63;
  int nl = threadIdx.x >> 6;
  for (int base = blockIdx.x * 4; base < N; base += gridDim.x * 4) {
    __syncthreads();
    int gi = base * 64 + threadIdx.x;
    Xl[threadIdx.x] = (gi < N * 64) ? X[gi] : 0.f;
    __syncthreads();
    int v = base + nl;
    if (v < N) {
      float acc = 0.f;
#pragma unroll
      for (int k = 0; k < 64; k += 4) {
        acc = fmaf(Xl[nl * 64 + k + 0], Wl[(k + 0) * 64 + j], acc);
        acc = fmaf(Xl[nl * 64 + k + 1], Wl[(k + 1) * 64 + j], acc);
        acc = fmaf(Xl[nl * 64 + k + 2], Wl[(k + 2) * 64 + j], acc);
        acc = fmaf(Xl[nl * 64 + k + 3], Wl[(k + 3) * 64 + j], acc);
      }
      H[v * 64 + j] = acc;
    }
  }
}

// Pull-mode aggregation: one wave per node, lane = feature; no float atomics.
template <bool RELU>
__global__ __launch_bounds__(256) void k_agg(const float* __restrict__ H,
                                             const int* __restrict__ csr,
                                             const int* __restrict__ off,
                                             const int* __restrict__ cnt,
                                             const float* __restrict__ dinv,
                                             const float* __restrict__ bias,
                                             float* __restrict__ out, int N) {
  int wid = (blockIdx.x * blockDim.x + threadIdx.x) >> 6;
  int lane = threadIdx.x & 63;
  if (wid >= N) return;
  float dv = dinv[wid];
  float acc = H[wid * 64 + lane] * (dv * dv);  // self-loop
  int beg = off[wid];
  int num = cnt[wid];
  int i = 0;
  for (; i + 4 <= num; i += 4) {
    int s0 = csr[beg + i + 0], s1 = csr[beg + i + 1];
    int s2 = csr[beg + i + 2], s3 = csr[beg + i + 3];
    float w0 = dinv[s0], w1 = dinv[s1], w2 = dinv[s2], w3 = dinv[s3];
    float h0 = H[s0 * 64 + lane], h1 = H[s1 * 64 + lane];
    float h2 = H[s2 * 64 + lane], h3 = H[s3 * 64 + lane];
    acc = fmaf(h0, w0 * dv, acc);
    acc = fmaf(h1, w1 * dv, acc);
    acc = fmaf(h2, w2 * dv, acc);
    acc = fmaf(h3, w3 * dv, acc);
  }
  for (; i < num; ++i) {
    int s = csr[beg + i];
    acc = fmaf(H[s * 64 + lane], dinv[s] * dv, acc);
  }
  acc += bias[lane];
  if (RELU) acc = fmaxf(acc, 0.f);
  out[wid * 64 + lane] = acc;
}

extern "C" void kernel_launch(void* const* d_in, const int* in_sizes, int n_in,
                              void* d_out, int out_size, void* d_ws, size_t ws_size,
                              hipStream_t stream) {
  const float* x  = (const float*)d_in[0];
  const float* W1 = (const float*)d_in[1];
  const float* b1 = (const float*)d_in[2];
  const float* W2 = (const float*)d_in[3];
  const float* b2 = (const float*)d_in[4];
  const int*   e0 = (const int*)d_in[5];
  const int*   e1 = (const int*)d_in[6];
  float* out = (float*)d_out;

  const int N = in_sizes[0] / 64;   // 100000
  const int E = in_sizes[5] / 2;    // 3200000
  const int B = (N + NPB - 1) / NPB;  // 391 buckets
  const int* src0 = e0;     const int* dst0 = e0 + E;
  const int* src1 = e1;     const int* dst1 = e1 + E;

  char* w = (char*)d_ws;
  size_t o = 0;
  auto carve = [&](size_t bytes) -> void* {
    void* p = w + o;
    o = (o + bytes + 255) & ~(size_t)255;
    return p;
  };
  // zero-init region: cnt1,cnt2 (N each) + gcur0_1,gcur0_2 (512 each)
  int* zbase = (int*)carve(((size_t)2 * N + 1024) * 4);
  int* cnt1 = zbase;
  int* cnt2 = zbase + N;
  int* gc1  = zbase + 2 * N;
  int* gc2  = zbase + 2 * N + 512;
  int* off1 = (int*)carve((size_t)N * 4);
  int* off2 = (int*)carve((size_t)N * 4);
  float* dinv1 = (float*)carve((size_t)N * 4);
  float* dinv2 = (float*)carve((size_t)N * 4);
  int* bsum = (int*)carve(512 * 4);
  int* packed = (int*)carve((size_t)E * 4);
  int* csr1 = (int*)carve((size_t)E * 4);
  int* csr2 = (int*)carve((size_t)E * 4);
  float* H = (float*)carve((size_t)N * 64 * 4);

  const int NB = (N + 1023) / 1024;        // 98
  const int nblk = (N + 255) / 256;
  const int aggblk = (N * 64 + 255) / 256; // 25000
  const int sblk = (E + CHUNK - 1) / CHUNK; // 196

  hipMemsetAsync(zbase, 0, ((size_t)2 * N + 1024) * 4, stream);

  // degree + scan (both layers)
  k_hist<<<2048, 256, 0, stream>>>(dst0, cnt1, E);
  k_hist<<<2048, 256, 0, stream>>>(dst1, cnt2, E);
  k_dinv<<<nblk, 256, 0, stream>>>(cnt1, dinv1, N);
  k_dinv<<<nblk, 256, 0, stream>>>(cnt2, dinv2, N);
  k_scan1<<<NB, 256, 0, stream>>>(cnt1, off1, bsum, N);
  k_scan2<<<1, 128, 0, stream>>>(bsum, NB);
  k_scan3<<<nblk, 256, 0, stream>>>(off1, bsum, N);
  k_scan1<<<NB, 256, 0, stream>>>(cnt2, off2, bsum, N);
  k_scan2<<<1, 128, 0, stream>>>(bsum, NB);
  k_scan3<<<nblk, 256, 0, stream>>>(off2, bsum, N);

  // layer 1: partition -> fill -> gemm -> aggregate(+relu)
  k_bscatter<<<sblk, 256, 0, stream>>>(src0, dst0, off1, gc1, packed, E, B);
  k_fill2<<<B, 256, 0, stream>>>(packed, off1, csr1, N, E, B);
  k_gemm64<<<2048, 256, 0, stream>>>(x, W1, H, N);
  k_agg<true><<<aggblk, 256, 0, stream>>>(H, csr1, off1, cnt1, dinv1, b1, out, N);

  // layer 2
  k_bscatter<<<sblk, 256, 0, stream>>>(src1, dst1, off2, gc2, packed, E, B);
  k_fill2<<<B, 256, 0, stream>>>(packed, off2, csr2, N, E, B);
  k_gemm64<<<2048, 256, 0, stream>>>(out, W2, H, N);
  k_agg<false><<<aggblk, 256, 0, stream>>>(H, csr2, off2, cnt2, dinv2, b2, out, N);
}

// Round 3
// 643.065 us; speedup vs baseline: 1.7689x; 1.4139x over previous
//
#include <hip/hip_runtime.h>

// 2-layer GCN: out = gcn(relu(gcn(x,W1,b1,e0)), W2, b2, e1)
// R1: atomic-cursor CSR fill had 16x write-amp -> two-level bucket partition.
// R2: per-node global-atomic histogram had 250x write-amp (100MB for 400KB) ->
//     bucket-level histogram (391 bins, LDS+rare global atomics) + per-bucket
//     fused finalize: LDS node counts, LDS scan, coalesced off/dinv write,
//     private-window csr fill. Zero node-granular global atomics anywhere.
//     dinv folded into GEMM epilogue (H' = h*dinv) -> agg needs no dinv[s]
//     gathers; agg batches csr reads (64/wave-load) and shfl-broadcasts.

#define NPB   256   // nodes per bucket
#define BSH   8
#define BMSK  255
#define EPT   64    // edges per thread in k_bscatter
#define CHUNK (EPT * 256)

// Bucket histogram for both layers in one launch (layer = blockIdx.y).
__global__ __launch_bounds__(256) void k_bhist(const int* __restrict__ dst0,
                                               const int* __restrict__ dst1,
                                               int* __restrict__ bcnt0,
                                               int* __restrict__ bcnt1,
                                               int E, int B) {
  __shared__ int h[512];
  const int* dst = blockIdx.y ? dst1 : dst0;
  int* bcnt = blockIdx.y ? bcnt1 : bcnt0;
  for (int b = threadIdx.x; b < 512; b += 256) h[b] = 0;
  __syncthreads();
  int stride = gridDim.x * blockDim.x;
  for (int i = blockIdx.x * blockDim.x + threadIdx.x; i < E; i += stride)
    atomicAdd(&h[dst[i] >> BSH], 1);
  __syncthreads();
  for (int b = threadIdx.x; b < B; b += 256) {
    int c = h[b];
    if (c) atomicAdd(&bcnt[b], c);
  }
}

// Scan bucket counts -> bbase (exclusive), seed gcur. One block per layer.
__global__ __launch_bounds__(512) void k_bscan(const int* __restrict__ bcnt0,
                                               const int* __restrict__ bcnt1,
                                               int* __restrict__ bbase0,
                                               int* __restrict__ bbase1,
                                               int* __restrict__ gcur0,
                                               int* __restrict__ gcur1,
                                               int B, int E) {
  __shared__ int tmp[512];
  const int* bcnt = blockIdx.x ? bcnt1 : bcnt0;
  int* bbase = blockIdx.x ? bbase1 : bbase0;
  int* gcur = blockIdx.x ? gcur1 : gcur0;
  int t = threadIdx.x;
  int v = (t < B) ? bcnt[t] : 0;
  tmp[t] = v;
  __syncthreads();
#pragma unroll
  for (int d = 1; d < 512; d <<= 1) {
    int y = (t >= d) ? tmp[t - d] : 0;
    __syncthreads();
    tmp[t] += y;
    __syncthreads();
  }
  if (t < B) {
    int e = tmp[t] - v;  // exclusive
    bbase[t] = e;
    gcur[t] = e;
  }
  if (t == 0) bbase[B] = E;
}

// Partition edges into dst-buckets. Packed entry: (src<<8) | (dst&255).
__global__ __launch_bounds__(256) void k_bscatter(const int* __restrict__ src,
                                                  const int* __restrict__ dst,
                                                  int* __restrict__ gcur,
                                                  int* __restrict__ packed,
                                                  int E, int B) {
  __shared__ int bh[512];
  __shared__ int bbase[512];
  int t = threadIdx.x;
  for (int b = t; b < B; b += 256) bh[b] = 0;
  __syncthreads();
  int e0 = blockIdx.x * CHUNK;
#pragma unroll 4
  for (int k = 0; k < EPT; ++k) {
    int i = e0 + k * 256 + t;
    if (i < E) atomicAdd(&bh[dst[i] >> BSH], 1);
  }
  __syncthreads();
  for (int b = t; b < B; b += 256) {
    int c = bh[b];
    if (c) bbase[b] = atomicAdd(&gcur[b], c);
    bh[b] = 0;  // reuse as local cursor
  }
  __syncthreads();
#pragma unroll 4
  for (int k = 0; k < EPT; ++k) {
    int i = e0 + k * 256 + t;
    if (i < E) {
      int d = dst[i];
      int b = d >> BSH;
      int loc = atomicAdd(&bh[b], 1);
      packed[bbase[b] + loc] = (src[i] << BSH) | (d & BMSK);
    }
  }
}

// Per-bucket finalize: LDS node counts -> LDS scan -> off/dinv (coalesced)
// -> csr fine-fill in this bucket's private contiguous window.
__global__ __launch_bounds__(256) void k_bfin(const int* __restrict__ packed,
                                              const int* __restrict__ bbase,
                                              int* __restrict__ off,
                                              float* __restrict__ dinv,
                                              int* __restrict__ csr,
                                              int N, int B) {
  __shared__ int cntL[NPB];
  __shared__ int wsum[4];
  int t = threadIdx.x;
  int b = blockIdx.x;
  int beg = bbase[b], end = bbase[b + 1];
  cntL[t] = 0;
  __syncthreads();
  for (int i = beg + t; i < end; i += 256)
    atomicAdd(&cntL[packed[i] & BMSK], 1);
  __syncthreads();
  int c = cntL[t];
  int lane = t & 63, wid = t >> 6;
  int x = c;
#pragma unroll
  for (int d = 1; d < 64; d <<= 1) {
    int y = __shfl_up(x, d, 64);
    if (lane >= d) x += y;
  }
  if (lane == 63) wsum[wid] = x;
  __syncthreads();
  int wofs = 0;
  for (int ww = 0; ww < wid; ++ww) wofs += wsum[ww];
  int excl = beg + wofs + x - c;  // global exclusive prefix for node (b<<8)+t
  int v = (b << BSH) + t;
  if (v < N) {
    off[v] = excl;
    dinv[v] = rsqrtf((float)(c + 1));  // +1 self-loop
  }
  if (b == B - 1 && t == 0) off[N] = end;
  __syncthreads();
  cntL[t] = excl;  // reuse as fill cursor
  __syncthreads();
  for (int i = beg + t; i < end; i += 256) {
    int e = packed[i];
    int p = atomicAdd(&cntL[e & BMSK], 1);
    csr[p] = e >> BSH;
  }
}

// H'[v] = (X @ W)[v] * dinv[v].  W (16KB) in LDS; 4 nodes per block-iter.
__global__ __launch_bounds__(256) void k_gemm64(const float* __restrict__ X,
                                                const float* __restrict__ W,
                                                const float* __restrict__ dinv,
                                                float* __restrict__ H, int N) {
  __shared__ float Wl[4096];
  __shared__ float Xl[256];
  for (int t = threadIdx.x; t < 4096; t += 256) Wl[t] = W[t];
  int j = threadIdx.x & 63;
  int nl = threadIdx.x >> 6;
  for (int base = blockIdx.x * 4; base < N; base += gridDim.x * 4) {
    __syncthreads();
    int gi = base * 64 + threadIdx.x;
    Xl[threadIdx.x] = (gi < N * 64) ? X[gi] : 0.f;
    __syncthreads();
    int v = base + nl;
    if (v < N) {
      float acc = 0.f;
#pragma unroll
      for (int k = 0; k < 64; k += 4) {
        acc = fmaf(Xl[nl * 64 + k + 0], Wl[(k + 0) * 64 + j], acc);
        acc = fmaf(Xl[nl * 64 + k + 1], Wl[(k + 1) * 64 + j], acc);
        acc = fmaf(Xl[nl * 64 + k + 2], Wl[(k + 2) * 64 + j], acc);
        acc = fmaf(Xl[nl * 64 + k + 3], Wl[(k + 3) * 64 + j], acc);
      }
      H[v * 64 + j] = acc * dinv[v];
    }
  }
}

// Pull aggregation: one wave per node, lane = feature.
// out[v] = (sum_{s in N(v)} H'[s] + H'[v]) * dinv[v] + b   (H' pre-scaled)
// csr indices loaded 64-per-wave-load, distributed via shfl -> 1 VMEM op/edge.
template <bool RELU>
__global__ __launch_bounds__(256) void k_agg(const float* __restrict__ H,
                                             const int* __restrict__ csr,
                                             const int* __restrict__ off,
                                             const float* __restrict__ dinv,
                                             const float* __restrict__ bias,
                                             float* __restrict__ out, int N) {
  int wid = (blockIdx.x * blockDim.x + threadIdx.x) >> 6;
  int lane = threadIdx.x & 63;
  if (wid >= N) return;
  int beg = off[wid];
  int num = off[wid + 1] - beg;
  float acc = H[wid * 64 + lane];  // self-loop (pre-scaled)
  for (int base = 0; base < num; base += 64) {
    int navail = min(64, num - base);
    int sv = (base + lane < num) ? csr[beg + base + lane] : 0;
    int j = 0;
    for (; j + 4 <= navail; j += 4) {
      int s0 = __shfl(sv, j + 0), s1 = __shfl(sv, j + 1);
      int s2 = __shfl(sv, j + 2), s3 = __shfl(sv, j + 3);
      float h0 = H[s0 * 64 + lane], h1 = H[s1 * 64 + lane];
      float h2 = H[s2 * 64 + lane], h3 = H[s3 * 64 + lane];
      acc += h0; acc += h1; acc += h2; acc += h3;
    }
    for (; j < navail; ++j) acc += H[__shfl(sv, j) * 64 + lane];
  }
  acc = fmaf(acc, dinv[wid], bias[lane]);
  if (RELU) acc = fmaxf(acc, 0.f);
  out[wid * 64 + lane] = acc;
}

extern "C" void kernel_launch(void* const* d_in, const int* in_sizes, int n_in,
                              void* d_out, int out_size, void* d_ws, size_t ws_size,
                              hipStream_t stream) {
  const float* x  = (const float*)d_in[0];
  const float* W1 = (const float*)d_in[1];
  const float* b1 = (const float*)d_in[2];
  const float* W2 = (const float*)d_in[3];
  const float* b2 = (const float*)d_in[4];
  const int*   e0 = (const int*)d_in[5];
  const int*   e1 = (const int*)d_in[6];
  float* out = (float*)d_out;

  const int N = in_sizes[0] / 64;      // 100000
  const int E = in_sizes[5] / 2;       // 3200000
  const int B = (N + NPB - 1) / NPB;   // 391
  const int* src0 = e0;     const int* dst0 = e0 + E;
  const int* src1 = e1;     const int* dst1 = e1 + E;

  char* w = (char*)d_ws;
  size_t o = 0;
  auto carve = [&](size_t bytes) -> void* {
    void* p = w + o;
    o = (o + bytes + 255) & ~(size_t)255;
    return p;
  };
  int* bcnt01 = (int*)carve(1024 * 4);        // zero-init: bcnt0|bcnt1
  int* bcnt0 = bcnt01;
  int* bcnt1 = bcnt01 + 512;
  int* gcur0 = (int*)carve(512 * 4);
  int* gcur1 = (int*)carve(512 * 4);
  int* bbase0 = (int*)carve(513 * 4);
  int* bbase1 = (int*)carve(513 * 4);
  int* off1 = (int*)carve((size_t)(N + 1) * 4);
  int* off2 = (int*)carve((size_t)(N + 1) * 4);
  float* dinv1 = (float*)carve((size_t)N * 4);
  float* dinv2 = (float*)carve((size_t)N * 4);
  int* packed = (int*)carve((size_t)E * 4);   // shared between layers
  int* csr1 = (int*)carve((size_t)E * 4);
  int* csr2 = (int*)carve((size_t)E * 4);
  float* H = (float*)carve((size_t)N * 64 * 4);

  const int aggblk = (N * 64 + 255) / 256;     // 25000
  const int sblk = (E + CHUNK - 1) / CHUNK;    // 196

  hipMemsetAsync(bcnt01, 0, 1024 * 4, stream);

  // bucket histogram + scan, both layers
  k_bhist<<<dim3(512, 2), 256, 0, stream>>>(dst0, dst1, bcnt0, bcnt1, E, B);
  k_bscan<<<2, 512, 0, stream>>>(bcnt0, bcnt1, bbase0, bbase1, gcur0, gcur1, B, E);

  // layer 1
  k_bscatter<<<sblk, 256, 0, stream>>>(src0, dst0, gcur0, packed, E, B);
  k_bfin<<<B, 256, 0, stream>>>(packed, bbase0, off1, dinv1, csr1, N, B);
  k_gemm64<<<2048, 256, 0, stream>>>(x, W1, dinv1, H, N);
  k_agg<true><<<aggblk, 256, 0, stream>>>(H, csr1, off1, dinv1, b1, out, N);

  // layer 2 (packed reused; stream order serializes)
  k_bscatter<<<sblk, 256, 0, stream>>>(src1, dst1, gcur1, packed, E, B);
  k_bfin<<<B, 256, 0, stream>>>(packed, bbase1, off2, dinv2, csr2, N, B);
  k_gemm64<<<2048, 256, 0, stream>>>(out, W2, dinv2, H, N);
  k_agg<false><<<aggblk, 256, 0, stream>>>(H, csr2, off2, dinv2, b2, out, N);
}

// Round 4
// 619.947 us; speedup vs baseline: 1.8348x; 1.0373x over previous
//
#include <hip/hip_runtime.h>
#include <hip/hip_fp16.h>

// 2-layer GCN: out = gcn(relu(gcn(x,W1,b1,e0)), W2, b2, e1)
// R1: atomic-cursor CSR fill -> 16x write-amp -> two-level bucket partition.
// R2: node-granular global-atomic histogram -> 250x write-amp -> bucket-level
//     histogram + per-bucket fused finalize; dinv folded into GEMM epilogue.
// R3: k_bfin parallelism-starved (391 blocks, 1.4% occ) -> NPB 256->64
//     (1563 buckets, 4x blocks, 4x shorter serial loops). k_agg L2-miss
//     bound on 256B fp32 row gathers -> H' stored fp16 (128B rows, fits
//     XCD L2 2x better); fp32 accumulate preserved.

#define NPB   64    // nodes per bucket
#define BSH   6
#define BMSK  63
#define MAXB  2048  // >= B = ceil(100000/64) = 1563
#define EPT   64    // edges per thread in k_bscatter
#define CHUNK (EPT * 256)

// Bucket histogram for both layers in one launch (layer = blockIdx.y).
__global__ __launch_bounds__(256) void k_bhist(const int* __restrict__ dst0,
                                               const int* __restrict__ dst1,
                                               int* __restrict__ bcnt0,
                                               int* __restrict__ bcnt1,
                                               int E, int B) {
  __shared__ int h[MAXB];
  const int* dst = blockIdx.y ? dst1 : dst0;
  int* bcnt = blockIdx.y ? bcnt1 : bcnt0;
  for (int b = threadIdx.x; b < B; b += 256) h[b] = 0;
  __syncthreads();
  int stride = gridDim.x * blockDim.x;
  for (int i = blockIdx.x * blockDim.x + threadIdx.x; i < E; i += stride)
    atomicAdd(&h[dst[i] >> BSH], 1);
  __syncthreads();
  for (int b = threadIdx.x; b < B; b += 256) {
    int c = h[b];
    if (c) atomicAdd(&bcnt[b], c);
  }
}

// Single-block scan of up to 2048 bucket counts; one block per layer.
__global__ __launch_bounds__(512) void k_bscan(const int* __restrict__ bcnt0,
                                               const int* __restrict__ bcnt1,
                                               int* __restrict__ bbase0,
                                               int* __restrict__ bbase1,
                                               int* __restrict__ gcur0,
                                               int* __restrict__ gcur1,
                                               int B, int E) {
  __shared__ int wsum[8];
  const int* bcnt = blockIdx.x ? bcnt1 : bcnt0;
  int* bbase = blockIdx.x ? bbase1 : bbase0;
  int* gcur = blockIdx.x ? gcur1 : gcur0;
  int t = threadIdx.x;
  int i0 = t * 4;
  int v0 = (i0 + 0 < B) ? bcnt[i0 + 0] : 0;
  int v1 = (i0 + 1 < B) ? bcnt[i0 + 1] : 0;
  int v2 = (i0 + 2 < B) ? bcnt[i0 + 2] : 0;
  int v3 = (i0 + 3 < B) ? bcnt[i0 + 3] : 0;
  int tsum = v0 + v1 + v2 + v3;
  int lane = t & 63, wid = t >> 6;
  int x = tsum;
#pragma unroll
  for (int d = 1; d < 64; d <<= 1) {
    int y = __shfl_up(x, d, 64);
    if (lane >= d) x += y;
  }
  if (lane == 63) wsum[wid] = x;
  __syncthreads();
  int wofs = 0;
  for (int ww = 0; ww < wid; ++ww) wofs += wsum[ww];
  int excl = wofs + x - tsum;
  if (i0 + 0 < B) { bbase[i0 + 0] = excl;                gcur[i0 + 0] = excl; }
  if (i0 + 1 < B) { bbase[i0 + 1] = excl + v0;           gcur[i0 + 1] = excl + v0; }
  if (i0 + 2 < B) { bbase[i0 + 2] = excl + v0 + v1;      gcur[i0 + 2] = excl + v0 + v1; }
  if (i0 + 3 < B) { bbase[i0 + 3] = excl + v0 + v1 + v2; gcur[i0 + 3] = excl + v0 + v1 + v2; }
  if (t == 0) bbase[B] = E;
}

// Partition edges into dst-buckets. Packed entry: (src<<6) | (dst&63).
__global__ __launch_bounds__(256) void k_bscatter(const int* __restrict__ src,
                                                  const int* __restrict__ dst,
                                                  int* __restrict__ gcur,
                                                  int* __restrict__ packed,
                                                  int E, int B) {
  __shared__ int bh[MAXB];
  __shared__ int bbaseL[MAXB];
  int t = threadIdx.x;
  for (int b = t; b < B; b += 256) bh[b] = 0;
  __syncthreads();
  int e0 = blockIdx.x * CHUNK;
#pragma unroll 4
  for (int k = 0; k < EPT; ++k) {
    int i = e0 + k * 256 + t;
    if (i < E) atomicAdd(&bh[dst[i] >> BSH], 1);
  }
  __syncthreads();
  for (int b = t; b < B; b += 256) {
    int c = bh[b];
    if (c) bbaseL[b] = atomicAdd(&gcur[b], c);
    bh[b] = 0;  // reuse as local cursor
  }
  __syncthreads();
#pragma unroll 4
  for (int k = 0; k < EPT; ++k) {
    int i = e0 + k * 256 + t;
    if (i < E) {
      int d = dst[i];
      int b = d >> BSH;
      int loc = atomicAdd(&bh[b], 1);
      packed[bbaseL[b] + loc] = (src[i] << BSH) | (d & BMSK);
    }
  }
}

// Per-bucket finalize: LDS node counts -> scan -> off/dinv -> csr fill in
// this bucket's private ~8KB window. 1563 blocks, ~2048 edges each.
__global__ __launch_bounds__(256) void k_bfin(const int* __restrict__ packed,
                                              const int* __restrict__ bbase,
                                              int* __restrict__ off,
                                              float* __restrict__ dinv,
                                              int* __restrict__ csr,
                                              int N, int B) {
  __shared__ int cntL[NPB];
  __shared__ int curL[NPB];
  int t = threadIdx.x;
  int b = blockIdx.x;
  int beg = bbase[b], end = bbase[b + 1];
  if (t < NPB) cntL[t] = 0;
  __syncthreads();
  for (int i = beg + t; i < end; i += 256)
    atomicAdd(&cntL[packed[i] & BMSK], 1);
  __syncthreads();
  if (t < NPB) {  // wave 0: scan 64 counts
    int c = cntL[t];
    int x = c;
#pragma unroll
    for (int d = 1; d < 64; d <<= 1) {
      int y = __shfl_up(x, d, 64);
      if (t >= d) x += y;
    }
    int excl = beg + x - c;
    int v = (b << BSH) + t;
    if (v < N) {
      off[v] = excl;
      dinv[v] = rsqrtf((float)(c + 1));  // +1 self-loop
    }
    curL[t] = excl;
    if (b == B - 1 && t == 0) off[N] = end;
  }
  __syncthreads();
  for (int i = beg + t; i < end; i += 256) {
    int e = packed[i];
    int p = atomicAdd(&curL[e & BMSK], 1);
    csr[p] = e >> BSH;
  }
}

// H'[v] = fp16((X @ W)[v] * dinv[v]).  W (16KB) in LDS; 4 nodes/block-iter.
__global__ __launch_bounds__(256) void k_gemm64(const float* __restrict__ X,
                                                const float* __restrict__ W,
                                                const float* __restrict__ dinv,
                                                __half* __restrict__ H, int N) {
  __shared__ float Wl[4096];
  __shared__ float Xl[256];
  for (int t = threadIdx.x; t < 4096; t += 256) Wl[t] = W[t];
  int j = threadIdx.x & 63;
  int nl = threadIdx.x >> 6;
  for (int base = blockIdx.x * 4; base < N; base += gridDim.x * 4) {
    __syncthreads();
    int gi = base * 64 + threadIdx.x;
    Xl[threadIdx.x] = (gi < N * 64) ? X[gi] : 0.f;
    __syncthreads();
    int v = base + nl;
    if (v < N) {
      float acc = 0.f;
#pragma unroll
      for (int k = 0; k < 64; k += 4) {
        acc = fmaf(Xl[nl * 64 + k + 0], Wl[(k + 0) * 64 + j], acc);
        acc = fmaf(Xl[nl * 64 + k + 1], Wl[(k + 1) * 64 + j], acc);
        acc = fmaf(Xl[nl * 64 + k + 2], Wl[(k + 2) * 64 + j], acc);
        acc = fmaf(Xl[nl * 64 + k + 3], Wl[(k + 3) * 64 + j], acc);
      }
      H[v * 64 + j] = __float2half_rn(acc * dinv[v]);
    }
  }
}

// Pull aggregation: one wave per node, lane = feature; fp16 gathers,
// fp32 accumulate. csr read 64-per-wave-load, shfl-broadcast.
template <bool RELU>
__global__ __launch_bounds__(256) void k_agg(const __half* __restrict__ H,
                                             const int* __restrict__ csr,
                                             const int* __restrict__ off,
                                             const float* __restrict__ dinv,
                                             const float* __restrict__ bias,
                                             float* __restrict__ out, int N) {
  int wid = (blockIdx.x * blockDim.x + threadIdx.x) >> 6;
  int lane = threadIdx.x & 63;
  if (wid >= N) return;
  int beg = off[wid];
  int num = off[wid + 1] - beg;
  float acc = __half2float(H[wid * 64 + lane]);  // self-loop (pre-scaled)
  for (int base = 0; base < num; base += 64) {
    int navail = min(64, num - base);
    int sv = (base + lane < num) ? csr[beg + base + lane] : 0;
    int j = 0;
    for (; j + 4 <= navail; j += 4) {
      int s0 = __shfl(sv, j + 0), s1 = __shfl(sv, j + 1);
      int s2 = __shfl(sv, j + 2), s3 = __shfl(sv, j + 3);
      float h0 = __half2float(H[s0 * 64 + lane]);
      float h1 = __half2float(H[s1 * 64 + lane]);
      float h2 = __half2float(H[s2 * 64 + lane]);
      float h3 = __half2float(H[s3 * 64 + lane]);
      acc += h0; acc += h1; acc += h2; acc += h3;
    }
    for (; j < navail; ++j) acc += __half2float(H[__shfl(sv, j) * 64 + lane]);
  }
  acc = fmaf(acc, dinv[wid], bias[lane]);
  if (RELU) acc = fmaxf(acc, 0.f);
  out[wid * 64 + lane] = acc;
}

extern "C" void kernel_launch(void* const* d_in, const int* in_sizes, int n_in,
                              void* d_out, int out_size, void* d_ws, size_t ws_size,
                              hipStream_t stream) {
  const float* x  = (const float*)d_in[0];
  const float* W1 = (const float*)d_in[1];
  const float* b1 = (const float*)d_in[2];
  const float* W2 = (const float*)d_in[3];
  const float* b2 = (const float*)d_in[4];
  const int*   e0 = (const int*)d_in[5];
  const int*   e1 = (const int*)d_in[6];
  float* out = (float*)d_out;

  const int N = in_sizes[0] / 64;      // 100000
  const int E = in_sizes[5] / 2;       // 3200000
  const int B = (N + NPB - 1) / NPB;   // 1563
  const int* src0 = e0;     const int* dst0 = e0 + E;
  const int* src1 = e1;     const int* dst1 = e1 + E;

  char* w = (char*)d_ws;
  size_t o = 0;
  auto carve = [&](size_t bytes) -> void* {
    void* p = w + o;
    o = (o + bytes + 255) & ~(size_t)255;
    return p;
  };
  int* bcnt01 = (int*)carve((size_t)2 * MAXB * 4);  // zero-init
  int* bcnt0 = bcnt01;
  int* bcnt1 = bcnt01 + MAXB;
  int* gcur0 = (int*)carve(MAXB * 4);
  int* gcur1 = (int*)carve(MAXB * 4);
  int* bbase0 = (int*)carve((MAXB + 1) * 4);
  int* bbase1 = (int*)carve((MAXB + 1) * 4);
  int* off1 = (int*)carve((size_t)(N + 1) * 4);
  int* off2 = (int*)carve((size_t)(N + 1) * 4);
  float* dinv1 = (float*)carve((size_t)N * 4);
  float* dinv2 = (float*)carve((size_t)N * 4);
  int* packed = (int*)carve((size_t)E * 4);   // shared between layers
  int* csr1 = (int*)carve((size_t)E * 4);
  int* csr2 = (int*)carve((size_t)E * 4);
  __half* H = (__half*)carve((size_t)N * 64 * 2);

  const int aggblk = (N * 64 + 255) / 256;     // 25000
  const int sblk = (E + CHUNK - 1) / CHUNK;    // 196

  hipMemsetAsync(bcnt01, 0, (size_t)2 * MAXB * 4, stream);

  // bucket histogram + scan, both layers
  k_bhist<<<dim3(512, 2), 256, 0, stream>>>(dst0, dst1, bcnt0, bcnt1, E, B);
  k_bscan<<<2, 512, 0, stream>>>(bcnt0, bcnt1, bbase0, bbase1, gcur0, gcur1, B, E);

  // layer 1
  k_bscatter<<<sblk, 256, 0, stream>>>(src0, dst0, gcur0, packed, E, B);
  k_bfin<<<B, 256, 0, stream>>>(packed, bbase0, off1, dinv1, csr1, N, B);
  k_gemm64<<<2048, 256, 0, stream>>>(x, W1, dinv1, H, N);
  k_agg<true><<<aggblk, 256, 0, stream>>>(H, csr1, off1, dinv1, b1, out, N);

  // layer 2 (packed reused; stream order serializes)
  k_bscatter<<<sblk, 256, 0, stream>>>(src1, dst1, gcur1, packed, E, B);
  k_bfin<<<B, 256, 0, stream>>>(packed, bbase1, off2, dinv2, csr2, N, B);
  k_gemm64<<<2048, 256, 0, stream>>>(out, W2, dinv2, H, N);
  k_agg<false><<<aggblk, 256, 0, stream>>>(H, csr2, off2, dinv2, b2, out, N);
}